// Round 3
// baseline (55.369 us; speedup 1.0000x reference)
//
#include <hip/hip_runtime.h>

// Problem constants (from reference)
#define B_IMG 8
#define C_IN  16
#define COUT  64
#define H0    36
#define H1    6
#define NB    6
#define NNODE 43            // 36 + 6 + 1 nodes per channel
// OH = OW = 16; 2048 pixel-rows total; output [8][64][16][16]

// d_ws layout:
//   float  wsf[COUT*NNODE*64]   per-(channel,node) sigmoid'd table, delta form:
//                               [ lo[k]=sig(w[k]) k<32 | dd[k]=sig(w[k+32])-sig(w[k]) ]
//   int    meta[COUT*H0*12]     per-(channel,L0-node) gather meta: 6 x {off, kh|kw<<8}
//   int    ch[COUT*79]          per-channel: [0]=usedCnt, [1..36]=usedList,
//                               [37..72]=idx1 remapped to slots, [73..78]=idx2
#define TBL_FLOATS (COUT*NNODE*64)
#define META_INTS  (COUT*H0*12)
#define CH_STRIDE  (1 + H0 + H1*NB + NB)   // 79

typedef float f32x2 __attribute__((ext_vector_type(2)));

__device__ __forceinline__ float sigf(float v) { return 1.0f / (1.0f + __expf(-v)); }

__global__ __launch_bounds__(256) void setup_kernel(
    const float* __restrict__ table0,
    const float* __restrict__ table1,
    const float* __restrict__ table2,
    const int*   __restrict__ idx0,
    const int*   __restrict__ idx1,
    const int*   __restrict__ idx2,
    float*       __restrict__ wsf)
{
    int id = blockIdx.x * 256 + threadIdx.x;
    const int NTBL = COUT * NNODE * 32;          // (t,node,k<32)
    const int META = COUT * H0 * NB;             // (t,n<36,i<6)
    int* wsI = (int*)(wsf + TBL_FLOATS);
    if (id < NTBL) {
        int k    = id & 31;
        int tn   = id >> 5;
        int node = tn % NNODE;
        int t    = tn / NNODE;
        const float* src;
        if (node < H0)         src = table0 + ((size_t)t*H0 + node) * 64;
        else if (node < H0+H1) src = table1 + ((size_t)t*H1 + (node - H0)) * 64;
        else                   src = table2 + (size_t)t * 64;
        float lo = sigf(src[k]);
        float hi = sigf(src[k + 32]);
        wsf[(size_t)tn*64 + k]      = lo;
        wsf[(size_t)tn*64 + 32 + k] = hi - lo;
    } else if (id < NTBL + META) {
        int m  = id - NTBL;
        int i  = m % NB;
        int nn = (m / NB) % H0;
        int t  = m / (NB * H0);
        int raw = idx0[(size_t)t*(H0*NB) + nn*NB + i];
        int c   = raw / 25;
        int rem = raw - c * 25;
        int kh  = rem / 5;
        int kw  = rem - kh * 5;
        wsI[((size_t)t*H0 + nn)*12 + i*2 + 0] = c*1024 + (kh - 2)*32 + (kw - 2);
        wsI[((size_t)t*H0 + nn)*12 + i*2 + 1] = kh | (kw << 8);
    } else if (id < NTBL + META + COUT) {
        int t = id - NTBL - META;                 // per-channel prune/remap
        int* ch = wsI + META_INTS + t*CH_STRIDE;
        unsigned long long mask = 0;
        for (int j = 0; j < H1*NB; ++j)
            mask |= 1ull << idx1[(size_t)t*(H1*NB) + j];
        int cnt = 0;
        for (int n = 0; n < H0; ++n)
            if ((mask >> n) & 1ull) ch[1 + cnt++] = n;
        ch[0] = cnt;
        for (int j = 0; j < H1*NB; ++j) {
            int raw = idx1[(size_t)t*(H1*NB) + j];
            ch[1 + H0 + j] = __popcll(mask & ((1ull << raw) - 1ull));
        }
        for (int i = 0; i < NB; ++i)
            ch[1 + H0 + H1*NB + i] = idx2[(size_t)t*NB + i];
    }
}

// 6-bit multilinear interp from delta-form table (global, wave-uniform broadcast).
// g[0] contracts the MSB ... g[5] the LSB, matching the reference einsum order.
__device__ __forceinline__ float lut_contract(const float* __restrict__ tb, const float g[NB]) {
    const float4* t4 = (const float4*)tb;
    f32x2 v[16];
    const float g0 = g[0];
#pragma unroll
    for (int q = 0; q < 8; ++q) {
        float4 lo4 = t4[q];
        float4 dd4 = t4[q + 8];
        v[2*q+0] = (f32x2){lo4.x, lo4.y} + (f32x2){dd4.x, dd4.y} * g0;   // pk_fma
        v[2*q+1] = (f32x2){lo4.z, lo4.w} + (f32x2){dd4.z, dd4.w} * g0;
    }
#pragma unroll
    for (int i = 1; i < 5; ++i) {
        const int vh = 16 >> i;
        const float gi = g[i];
#pragma unroll
        for (int r = 0; r < vh; ++r)
            v[r] += (v[r + vh] - v[r]) * gi;                              // pk_sub+pk_fma
    }
    return v[0].x + (v[0].y - v[0].x) * g[5];
}

// Block = one channel x 64 pixels; 4 waves = 4 node-lanes.
__global__ __launch_bounds__(256, 4) void lutconv_kernel(
    const float* __restrict__ x,
    const float* __restrict__ wsf,
    float*       __restrict__ out)
{
    __shared__ float h0s[H0*64];    // [slot][lane] — bank = lane, conflict-free
    __shared__ float h1s[H1*64];

    const int tid  = threadIdx.x;
    const int w    = tid >> 6;
    const int lane = tid & 63;
    const int t    = blockIdx.x & 63;         // channel
    const int g    = blockIdx.x >> 6;         // pixel group (64 rows)
    const int img  = g >> 2;
    const int p0   = (g & 3) * 64 + lane;     // pixel within image
    const int oh2  = (p0 >> 4) * 2;
    const int ow2  = (p0 & 15) * 2;
    const int base = img*(C_IN*32*32) + oh2*32 + ow2;

    int hm = 0, wm = 0;
#pragma unroll
    for (int k = 0; k < 5; ++k) {
        hm |= (((unsigned)(oh2 + k - 2) < 32u) ? 1 : 0) << k;
        wm |= (((unsigned)(ow2 + k - 2) < 32u) ? 1 : 0) << k;
    }

    const float* tblT  = wsf + (size_t)t * NNODE * 64;
    const int*   wsI   = (const int*)(wsf + TBL_FLOATS);
    const int*   metaT = wsI + (size_t)t * H0 * 12;
    const int*   chI   = wsI + META_INTS + (size_t)t * CH_STRIDE;
    const int    nU    = chI[0];

    // ---- layer 0: waves stride over used nodes ----
    for (int s = w; s < nU; s += 4) {
        const int n = chI[1 + s];
        const int4* mp = (const int4*)(metaT + n*12);
        int4 m01 = mp[0], m23 = mp[1], m45 = mp[2];
        float gg[NB];
        {
            int offs[NB] = {m01.x, m01.z, m23.x, m23.z, m45.x, m45.z};
            int pks [NB] = {m01.y, m01.w, m23.y, m23.w, m45.y, m45.w};
#pragma unroll
            for (int i = 0; i < NB; ++i) {
                int kh = pks[i] & 255, kw = pks[i] >> 8;
                bool ok = (((hm >> kh) & (wm >> kw)) & 1) != 0;
                float v = x[ok ? (base + offs[i]) : 0];
                gg[i] = ok ? v : 0.0f;
            }
        }
        h0s[s*64 + lane] = lut_contract(tblT + n*64, gg);
    }
    __syncthreads();

    // ---- layer 1: 6 nodes over 4 waves ----
    for (int n = w; n < H1; n += 4) {
        const int* i1 = chI + 1 + H0 + n*NB;
        float gg[NB];
#pragma unroll
        for (int i = 0; i < NB; ++i) gg[i] = h0s[i1[i]*64 + lane];
        h1s[n*64 + lane] = lut_contract(tblT + (H0 + n)*64, gg);
    }
    __syncthreads();

    // ---- layer 2: wave 0 ----
    if (w == 0) {
        const int* i2 = chI + 1 + H0 + H1*NB;
        float gg[NB];
#pragma unroll
        for (int i = 0; i < NB; ++i) gg[i] = h1s[i2[i]*64 + lane];
        out[((size_t)img*COUT + t)*256 + p0] = lut_contract(tblT + (H0 + H1)*64, gg);
    }
}

extern "C" void kernel_launch(void* const* d_in, const int* in_sizes, int n_in,
                              void* d_out, int out_size, void* d_ws, size_t ws_size,
                              hipStream_t stream) {
    const float* x      = (const float*)d_in[0];
    const int*   idx0   = (const int*)  d_in[1];
    const float* table0 = (const float*)d_in[2];
    const int*   idx1   = (const int*)  d_in[3];
    const float* table1 = (const float*)d_in[4];
    const int*   idx2   = (const int*)  d_in[5];
    const float* table2 = (const float*)d_in[6];
    float* out = (float*)d_out;
    float* wsf = (float*)d_ws;

    const int setup_items = COUT*NNODE*32 + COUT*H0*NB + COUT;
    setup_kernel<<<(setup_items + 255)/256, 256, 0, stream>>>(
        table0, table1, table2, idx0, idx1, idx2, wsf);
    lutconv_kernel<<<COUT * (2048/64), 256, 0, stream>>>(x, wsf, out);
}

// Round 4
// 32.889 us; speedup vs baseline: 1.6835x; 1.6835x over previous
//
#include <hip/hip_runtime.h>

// Problem constants
#define B_IMG 8
#define C_IN  16
#define COUT  64
#define H0    36
#define H1    6
#define NB    6
#define NNODE 43
// 2048 pixel-rows total (8 img x 256); output [8][64][16][16]

// d_ws layout (float indices unless noted):
//   xp   [0 .. XPN)                 padded x: [8][16][36][36], halo=2
//   tbl  [TBL_OFF .. +TBL_SZ)       per-(t,node) sigmoid'd delta tables: lo[32]|dd[32]
//   meta [META_OFF_I ints ..)       per-(t,L0-node): 6 gather offsets into xp (8-stride)
//   ch   [CH_OFF_I ints ..)         per-t: [0]=nU, [1..36]=usedList, [37..72]=idx1->slot
//   h0   [H0_OFF ..)                layer-0 outputs: [t][slot][2048]
#define XPN        (B_IMG*C_IN*36*36)        // 165888
#define TBL_OFF    XPN
#define TBL_SZ     (COUT*NNODE*64)           // 176128
#define META_OFF_I (TBL_OFF + TBL_SZ)
#define META_SZ    (COUT*H0*8)               // 18432 ints
#define CH_OFF_I   (META_OFF_I + META_SZ)
#define CH_STRIDE  80
#define CH_SZ      (COUT*CH_STRIDE)
#define H0_OFF     (CH_OFF_I + CH_SZ)

typedef float f32x2 __attribute__((ext_vector_type(2)));

__device__ __forceinline__ float sigf(float v) { return 1.0f / (1.0f + __expf(-v)); }

// 6-bit multilinear interp, table held in registers (delta form).
// g[0] contracts the MSB ... g[5] the LSB (matches reference einsum order).
__device__ __forceinline__ float lut_contract_reg(const float4 lo4[8], const float4 dd4[8],
                                                  const float g[NB]) {
    f32x2 v[16];
    const float g0 = g[0];
#pragma unroll
    for (int q = 0; q < 8; ++q) {
        v[2*q+0] = (f32x2){lo4[q].x, lo4[q].y} + (f32x2){dd4[q].x, dd4[q].y} * g0;
        v[2*q+1] = (f32x2){lo4[q].z, lo4[q].w} + (f32x2){dd4[q].z, dd4[q].w} * g0;
    }
#pragma unroll
    for (int i = 1; i < 5; ++i) {
        const int vh = 16 >> i;
        const float gi = g[i];
#pragma unroll
        for (int r = 0; r < vh; ++r)
            v[r] += (v[r + vh] - v[r]) * gi;
    }
    return v[0].x + (v[0].y - v[0].x) * g[5];
}

__device__ __forceinline__ void load_tbl(const float* __restrict__ tb,
                                         float4 lo4[8], float4 dd4[8]) {
    const float4* t4 = (const float4*)tb;
#pragma unroll
    for (int q = 0; q < 8; ++q) { lo4[q] = t4[q]; dd4[q] = t4[q + 8]; }
}

__global__ __launch_bounds__(256) void setup_kernel(
    const float* __restrict__ x,
    const float* __restrict__ t0,
    const float* __restrict__ t1,
    const float* __restrict__ t2,
    const int*   __restrict__ idx0,
    const int*   __restrict__ idx1,
    float*       __restrict__ ws)
{
    int id = blockIdx.x * 256 + threadIdx.x;
    int* wsI = (int*)ws;
    if (id < XPN) {                               // pad x -> xp [8][16][36][36]
        int img = id / 20736, r = id % 20736;
        int c   = r / 1296,  r2 = r % 1296;
        int ih  = r2 / 36,   iw = r2 % 36;
        int ihs = ih - 2,    iws = iw - 2;
        bool ok = ((unsigned)ihs < 32u) & ((unsigned)iws < 32u);
        ws[id] = ok ? x[((img*C_IN + c)*32 + ihs)*32 + iws] : 0.0f;
        return;
    }
    id -= XPN;
    if (id < COUT*NNODE*32) {                     // delta tables
        int k = id & 31, tn = id >> 5;
        int node = tn % NNODE, t = tn / NNODE;
        const float* src = (node < H0)    ? t0 + ((size_t)t*H0 + node)*64
                         : (node < H0+H1) ? t1 + ((size_t)t*H1 + node - H0)*64
                                          : t2 + (size_t)t*64;
        float lo = sigf(src[k]);
        float hi = sigf(src[k + 32]);
        ws[TBL_OFF + tn*64 + k]      = lo;
        ws[TBL_OFF + tn*64 + 32 + k] = hi - lo;
        return;
    }
    id -= COUT*NNODE*32;
    if (id < COUT*H0*NB) {                        // gather offsets into xp
        int i = id % NB, nn = (id/NB) % H0, t = id/(NB*H0);
        int raw = idx0[(size_t)t*(H0*NB) + nn*NB + i];
        int c = raw / 25, rem = raw - c*25, kh = rem / 5, kw = rem - kh*5;
        wsI[META_OFF_I + (t*H0 + nn)*8 + i] = c*1296 + kh*36 + kw;
        return;
    }
    id -= COUT*H0*NB;
    if (id < COUT) {                              // prune + remap per channel
        int t = id;
        int* ch = wsI + CH_OFF_I + t*CH_STRIDE;
        unsigned long long mask = 0;
        for (int j = 0; j < H1*NB; ++j) mask |= 1ull << idx1[(size_t)t*(H1*NB) + j];
        int cnt = 0;
        for (int n = 0; n < H0; ++n) if ((mask >> n) & 1ull) ch[1 + cnt++] = n;
        ch[0] = cnt;
        for (int j = 0; j < H1*NB; ++j) {
            int raw = idx1[(size_t)t*(H1*NB) + j];
            ch[1 + H0 + j] = __popcll(mask & ((1ull << raw) - 1ull));
        }
    }
}

// Layer 0: block = (slot s, channel t); 4 waves x 512 pixels each.
// Table lives in VGPRs for the whole pixel stream.
__global__ __launch_bounds__(256, 4) void lut0_kernel(
    const float* __restrict__ xp,
    const float* __restrict__ tbl,
    const int*   __restrict__ meta,
    const int*   __restrict__ ch,
    float*       __restrict__ h0out)
{
    const int t = blockIdx.x & 63;
    const int s = blockIdx.x >> 6;
    const int* chT = ch + t*CH_STRIDE;
    if (s >= chT[0]) return;
    const int n = __builtin_amdgcn_readfirstlane(chT[1 + s]);

    const int w = threadIdx.x >> 6, lane = threadIdx.x & 63;
    const int* mt = meta + (t*H0 + n)*8;
    const int off0 = mt[0], off1 = mt[1], off2 = mt[2];
    const int off3 = mt[3], off4 = mt[4], off5 = mt[5];

    float4 lo4[8], dd4[8];
    load_tbl(tbl + (t*NNODE + n)*64, lo4, dd4);

    float* h0p = h0out + (t*H0 + s)*2048;

    for (int it = 0; it < 8; ++it) {
        const int p   = (w << 9) + (it << 6) + lane;
        const int img = p >> 8, pix = p & 255;
        const int base = img*20736 + ((pix >> 4) << 1)*36 + ((pix & 15) << 1);
        float g[NB];
        g[0] = xp[base + off0]; g[1] = xp[base + off1]; g[2] = xp[base + off2];
        g[3] = xp[base + off3]; g[4] = xp[base + off4]; g[5] = xp[base + off5];
        h0p[p] = lut_contract_reg(lo4, dd4, g);
    }
}

// Layers 1+2: block = (pixel-group g of 64, channel t); waves split the 6 L1 nodes.
__global__ __launch_bounds__(256, 4) void lut12_kernel(
    const float* __restrict__ tbl,
    const int*   __restrict__ ch,
    const int*   __restrict__ idx2,
    const float* __restrict__ h0ws,
    float*       __restrict__ out)
{
    __shared__ float h1s[H1*64];
    const int t = blockIdx.x & 63;
    const int g = blockIdx.x >> 6;            // 0..31
    const int w = threadIdx.x >> 6, lane = threadIdx.x & 63;
    const int p = (g << 6) + lane;

    const int*   chT  = ch + t*CH_STRIDE;
    const float* h0T  = h0ws + t*H0*2048;
    const float* tblT = tbl + t*NNODE*64;

    for (int n = w; n < H1; n += 4) {
        float4 lo4[8], dd4[8];
        load_tbl(tblT + (H0 + n)*64, lo4, dd4);
        float gg[NB];
#pragma unroll
        for (int i = 0; i < NB; ++i) {
            int slot = chT[1 + H0 + n*NB + i];
            gg[i] = h0T[slot*2048 + p];
        }
        h1s[n*64 + lane] = lut_contract_reg(lo4, dd4, gg);
    }
    __syncthreads();

    if (w == 0) {
        float4 lo4[8], dd4[8];
        load_tbl(tblT + (H0 + H1)*64, lo4, dd4);
        float gg[NB];
#pragma unroll
        for (int i = 0; i < NB; ++i)
            gg[i] = h1s[idx2[t*NB + i]*64 + lane];
        const int img = p >> 8, pix = p & 255;
        out[(img*COUT + t)*256 + pix] = lut_contract_reg(lo4, dd4, gg);
    }
}

extern "C" void kernel_launch(void* const* d_in, const int* in_sizes, int n_in,
                              void* d_out, int out_size, void* d_ws, size_t ws_size,
                              hipStream_t stream) {
    const float* x      = (const float*)d_in[0];
    const int*   idx0   = (const int*)  d_in[1];
    const float* table0 = (const float*)d_in[2];
    const int*   idx1   = (const int*)  d_in[3];
    const float* table1 = (const float*)d_in[4];
    const int*   idx2   = (const int*)  d_in[5];
    const float* table2 = (const float*)d_in[6];
    float* out = (float*)d_out;
    float* ws  = (float*)d_ws;

    const int setup_items = XPN + COUT*NNODE*32 + COUT*H0*NB + COUT;
    setup_kernel<<<(setup_items + 255)/256, 256, 0, stream>>>(
        x, table0, table1, table2, idx0, idx1, ws);

    const float* xp    = ws;
    const float* tbl   = ws + TBL_OFF;
    const int*   meta  = (const int*)ws + META_OFF_I;
    const int*   ch    = (const int*)ws + CH_OFF_I;
    float*       h0ws  = ws + H0_OFF;

    lut0_kernel <<<H0*COUT, 256, 0, stream>>>(xp, tbl, meta, ch, h0ws);
    lut12_kernel<<<32*COUT, 256, 0, stream>>>(tbl, ch, (const int*)d_in[5], h0ws, out);
}

// Round 5
// 31.746 us; speedup vs baseline: 1.7441x; 1.0360x over previous
//
#include <hip/hip_runtime.h>

// Problem constants
#define B_IMG 8
#define C_IN  16
#define COUT  64
#define H0    36
#define H1    6
#define NB    6
#define NNODE 43
// 2048 pixel-rows (8 img x 256); output [8][64][16][16]

// d_ws layout (float indices unless noted):
//   xp   [0 .. XPN)            padded x: [8][16][36][36], halo=2
//   tbl  [TBL_OFF ..)          per-(t,node) sigmoid'd delta tables: lo[32]|dd[32]
//   meta [META_OFF_I ints ..)  per-(t,L0-node): 6 gather offsets into xp (8-stride)
//   ch   [CH_OFF_I ints ..)    per-t: [0]=nU, [1..36]=usedList, [37..72]=idx1->slot
#define XPN        (B_IMG*C_IN*36*36)        // 165888
#define TBL_OFF    XPN
#define TBL_SZ     (COUT*NNODE*64)           // 176128
#define META_OFF_I (TBL_OFF + TBL_SZ)
#define META_SZ    (COUT*H0*8)               // 18432 ints
#define CH_OFF_I   (META_OFF_I + META_SZ)
#define CH_STRIDE  80

typedef float f32x2 __attribute__((ext_vector_type(2)));

__device__ __forceinline__ float sigf(float v) { return 1.0f / (1.0f + __expf(-v)); }

// 6-bit multilinear interp, delta-form table in registers.
// g[0] contracts the MSB ... g[5] the LSB (matches reference einsum order).
__device__ __forceinline__ float lut_contract_reg(const float4 lo4[8], const float4 dd4[8],
                                                  const float g[NB]) {
    f32x2 v[16];
    const float g0 = g[0];
#pragma unroll
    for (int q = 0; q < 8; ++q) {
        v[2*q+0] = (f32x2){lo4[q].x, lo4[q].y} + (f32x2){dd4[q].x, dd4[q].y} * g0;
        v[2*q+1] = (f32x2){lo4[q].z, lo4[q].w} + (f32x2){dd4[q].z, dd4[q].w} * g0;
    }
#pragma unroll
    for (int i = 1; i < 5; ++i) {
        const int vh = 16 >> i;
        const float gi = g[i];
#pragma unroll
        for (int r = 0; r < vh; ++r)
            v[r] += (v[r + vh] - v[r]) * gi;
    }
    return v[0].x + (v[0].y - v[0].x) * g[5];
}

__device__ __forceinline__ void load_tbl(const float* __restrict__ tb,
                                         float4 lo4[8], float4 dd4[8]) {
    const float4* t4 = (const float4*)tb;
#pragma unroll
    for (int q = 0; q < 8; ++q) { lo4[q] = t4[q]; dd4[q] = t4[q + 8]; }
}

__global__ __launch_bounds__(256) void setup_kernel(
    const float* __restrict__ x,
    const float* __restrict__ t0,
    const float* __restrict__ t1,
    const float* __restrict__ t2,
    const int*   __restrict__ idx0,
    const int*   __restrict__ idx1,
    float*       __restrict__ ws)
{
    int id = blockIdx.x * 256 + threadIdx.x;
    int* wsI = (int*)ws;
    if (id < XPN) {                               // pad x -> xp [8][16][36][36]
        int img = id / 20736, r = id % 20736;
        int c   = r / 1296,  r2 = r % 1296;
        int ih  = r2 / 36,   iw = r2 % 36;
        int ihs = ih - 2,    iws = iw - 2;
        bool ok = ((unsigned)ihs < 32u) & ((unsigned)iws < 32u);
        ws[id] = ok ? x[((img*C_IN + c)*32 + ihs)*32 + iws] : 0.0f;
        return;
    }
    id -= XPN;
    if (id < COUT*NNODE*32) {                     // delta tables
        int k = id & 31, tn = id >> 5;
        int node = tn % NNODE, t = tn / NNODE;
        const float* src = (node < H0)    ? t0 + ((size_t)t*H0 + node)*64
                         : (node < H0+H1) ? t1 + ((size_t)t*H1 + node - H0)*64
                                          : t2 + (size_t)t*64;
        float lo = sigf(src[k]);
        float hi = sigf(src[k + 32]);
        ws[TBL_OFF + tn*64 + k]      = lo;
        ws[TBL_OFF + tn*64 + 32 + k] = hi - lo;
        return;
    }
    id -= COUT*NNODE*32;
    if (id < COUT*H0*NB) {                        // gather offsets into xp
        int i = id % NB, nn = (id/NB) % H0, t = id/(NB*H0);
        int raw = idx0[(size_t)t*(H0*NB) + nn*NB + i];
        int c = raw / 25, rem = raw - c*25, kh = rem / 5, kw = rem - kh*5;
        wsI[META_OFF_I + (t*H0 + nn)*8 + i] = c*1296 + kh*36 + kw;
        return;
    }
    id -= COUT*H0*NB;
    if (id < COUT) {                              // prune + remap per channel
        int t = id;
        int* ch = wsI + CH_OFF_I + t*CH_STRIDE;
        unsigned long long mask = 0;
        for (int j = 0; j < H1*NB; ++j) mask |= 1ull << idx1[(size_t)t*(H1*NB) + j];
        int cnt = 0;
        for (int n = 0; n < H0; ++n) if ((mask >> n) & 1ull) ch[1 + cnt++] = n;
        ch[0] = cnt;
        for (int j = 0; j < H1*NB; ++j) {
            int raw = idx1[(size_t)t*(H1*NB) + j];
            ch[1 + H0 + j] = __popcll(mask & ((1ull << raw) - 1ull));
        }
    }
}

// Fused layers 0+1+2. Block = (channel t, image img): 512 threads = 8 waves,
// 256 pixels. h0/h1 live in LDS; tables live in VGPRs per (wave,node).
__global__ __launch_bounds__(512, 4) void lutfused_kernel(
    const float* __restrict__ xp,
    const float* __restrict__ tbl,
    const int*   __restrict__ meta,
    const int*   __restrict__ ch,
    const int*   __restrict__ idx2,
    float*       __restrict__ out)
{
    __shared__ float h0s[H0*256];   // [slot][px] — bank = px, conflict-free
    __shared__ float h1s[H1*256];

    const int tid  = threadIdx.x;
    const int w    = tid >> 6;
    const int lane = tid & 63;
    const int t    = blockIdx.x & 63;
    const int img  = blockIdx.x >> 6;
    const int xb   = img * 20736;

    const int*   chT   = ch + t*CH_STRIDE;
    const int    nU    = chT[0];
    const float* tblT  = tbl + t*NNODE*64;
    const int*   metaT = meta + t*H0*8;

    // ---- phase A: layer 0; wave w owns slots [w*npw, min(..+npw, nU)) ----
    const int npw = (nU + 7) >> 3;
    const int sBeg = w * npw;
    const int sEnd = (sBeg + npw < nU) ? sBeg + npw : nU;
    for (int s = sBeg; s < sEnd; ++s) {
        const int n = chT[1 + s];
        const int* mt = metaT + n*8;
        const int off0 = mt[0], off1 = mt[1], off2 = mt[2];
        const int off3 = mt[3], off4 = mt[4], off5 = mt[5];
        float4 lo4[8], dd4[8];
        load_tbl(tblT + n*64, lo4, dd4);
#pragma unroll
        for (int c = 0; c < 4; ++c) {
            const int px = (c << 6) + lane;
            const int base = xb + ((px >> 4) << 1)*36 + ((px & 15) << 1);
            float g[NB];
            g[0] = xp[base + off0]; g[1] = xp[base + off1]; g[2] = xp[base + off2];
            g[3] = xp[base + off3]; g[4] = xp[base + off4]; g[5] = xp[base + off5];
            h0s[s*256 + px] = lut_contract_reg(lo4, dd4, g);
        }
    }
    __syncthreads();

    // ---- phase B: layer 1; waves 0..5 own one node each ----
    if (w < H1) {
        float4 lo4[8], dd4[8];
        load_tbl(tblT + (H0 + w)*64, lo4, dd4);
        const int* i1 = chT + 1 + H0 + w*NB;
        const int s0 = i1[0], s1 = i1[1], s2 = i1[2];
        const int s3 = i1[3], s4 = i1[4], s5 = i1[5];
#pragma unroll
        for (int c = 0; c < 4; ++c) {
            const int px = (c << 6) + lane;
            float g[NB];
            g[0] = h0s[s0*256 + px]; g[1] = h0s[s1*256 + px]; g[2] = h0s[s2*256 + px];
            g[3] = h0s[s3*256 + px]; g[4] = h0s[s4*256 + px]; g[5] = h0s[s5*256 + px];
            h1s[w*256 + px] = lut_contract_reg(lo4, dd4, g);
        }
    }
    __syncthreads();

    // ---- phase C: layer 2; waves 0..3 take one 64-px chunk each ----
    if (w < 4) {
        float4 lo4[8], dd4[8];
        load_tbl(tblT + (H0 + H1)*64, lo4, dd4);
        const int* i2 = idx2 + t*NB;
        const int px = (w << 6) + lane;
        float g[NB];
#pragma unroll
        for (int i = 0; i < NB; ++i) g[i] = h1s[i2[i]*256 + px];
        out[((size_t)img*COUT + t)*256 + px] = lut_contract_reg(lo4, dd4, g);
    }
}

extern "C" void kernel_launch(void* const* d_in, const int* in_sizes, int n_in,
                              void* d_out, int out_size, void* d_ws, size_t ws_size,
                              hipStream_t stream) {
    const float* x      = (const float*)d_in[0];
    const int*   idx0   = (const int*)  d_in[1];
    const float* table0 = (const float*)d_in[2];
    const int*   idx1   = (const int*)  d_in[3];
    const float* table1 = (const float*)d_in[4];
    const int*   idx2   = (const int*)  d_in[5];
    const float* table2 = (const float*)d_in[6];
    float* out = (float*)d_out;
    float* ws  = (float*)d_ws;

    const int setup_items = XPN + COUT*NNODE*32 + COUT*H0*NB + COUT;
    setup_kernel<<<(setup_items + 255)/256, 256, 0, stream>>>(
        x, table0, table1, table2, idx0, idx1, ws);

    const float* xp   = ws;
    const float* tbl  = ws + TBL_OFF;
    const int*   meta = (const int*)ws + META_OFF_I;
    const int*   ch   = (const int*)ws + CH_OFF_I;

    lutfused_kernel<<<COUT * B_IMG, 512, 0, stream>>>(xp, tbl, meta, ch, idx2, out);
}